// Round 5
// baseline (1681.557 us; speedup 1.0000x reference)
//
#include <hip/hip_runtime.h>
#include <hip/hip_bf16.h>
#include <math.h>

typedef __bf16 bf16;
typedef __bf16 v8bf __attribute__((ext_vector_type(8)));
typedef __bf16 v4bfv __attribute__((ext_vector_type(4)));
typedef float  v4f  __attribute__((ext_vector_type(4)));

#define B_   128
#define KK_  49
#define D_   512
#define E_   256
#define V_   10000
#define T_   20
#define NG_  2048   // 4*D
#define XK_  768    // E+D
#define VPAD 10112  // 79*128 (Wp rows padded)
#define NP_  128    // padded small-N

#define GLOAD_LDS16(gp, lp) \
    __builtin_amdgcn_global_load_lds((const __attribute__((address_space(1))) void*)(gp), \
                                     (__attribute__((address_space(3))) void*)(lp), 16, 0, 0)

__device__ inline v4bfv cvt4(float4 v) {
    v4bfv o; o[0] = (bf16)v.x; o[1] = (bf16)v.y; o[2] = (bf16)v.z; o[3] = (bf16)v.w;
    return o;
}

// ---------------------------------------------------------------------------
// Prep: fp32->bf16 conversions (float4-vectorized), padding, gather of LSTM
// input rows, packed init weights/biases.
// ---------------------------------------------------------------------------
__global__ void prep_kernel(
    const float* __restrict__ spatial, const float* __restrict__ gfeat,
    const int* __restrict__ caps, const float* __restrict__ emb,
    const float* __restrict__ W_init_h, const float* __restrict__ b_init_h,
    const float* __restrict__ W_init_m, const float* __restrict__ b_init_m,
    const float* __restrict__ W_ih, const float* __restrict__ b_ih,
    const float* __restrict__ W_hh, const float* __restrict__ b_hh,
    const float* __restrict__ Wv, const float* __restrict__ bv,
    const float* __restrict__ Wg, const float* __restrict__ bg,
    const float* __restrict__ Wp,
    bf16* __restrict__ Wp_b, bf16* __restrict__ Whh_b, bf16* __restrict__ Wih_b,
    bf16* __restrict__ Xin_b, bf16* __restrict__ Sp_b,
    bf16* __restrict__ Wv_b, bf16* __restrict__ Wg_b,
    bf16* __restrict__ Winit2_b, bf16* __restrict__ Gf_b,
    float* __restrict__ bias_comb, float* __restrict__ bias_init,
    float* __restrict__ bv_pad, float* __restrict__ bg_pad)
{
    const int stride = gridDim.x * blockDim.x;
    const int tid0 = blockIdx.x * blockDim.x + threadIdx.x;
    const float4 z4 = make_float4(0.f, 0.f, 0.f, 0.f);

    for (int i4 = tid0; i4 < VPAD * D_ / 4; i4 += stride) {
        int row = i4 >> 7;
        float4 v = (row < V_) ? ((const float4*)Wp)[i4] : z4;
        ((v4bfv*)Wp_b)[i4] = cvt4(v);
    }
    for (int i4 = tid0; i4 < NG_ * D_ / 4; i4 += stride)
        ((v4bfv*)Whh_b)[i4] = cvt4(((const float4*)W_hh)[i4]);
    for (int i4 = tid0; i4 < NG_ * XK_ / 4; i4 += stride)
        ((v4bfv*)Wih_b)[i4] = cvt4(((const float4*)W_ih)[i4]);
    // Xin rows r = t*128+b : [emb[captions[b,t]], global_feats[b]]
    for (int i4 = tid0; i4 < T_ * B_ * XK_ / 4; i4 += stride) {
        int r = i4 / (XK_ / 4), c4 = i4 - r * (XK_ / 4);
        int c = c4 * 4;
        int t = r >> 7, b = r & 127;
        float4 v;
        if (c < E_) v = *(const float4*)&emb[(long)caps[b * T_ + t] * E_ + c];
        else        v = *(const float4*)&gfeat[(long)b * D_ + (c - E_)];
        ((v4bfv*)Xin_b)[i4] = cvt4(v);
    }
    for (int i4 = tid0; i4 < B_ * KK_ * D_ / 4; i4 += stride)
        ((v4bfv*)Sp_b)[i4] = cvt4(((const float4*)spatial)[i4]);
    for (int i4 = tid0; i4 < NP_ * D_ / 4; i4 += stride) {
        int row = i4 >> 7;
        ((v4bfv*)Wv_b)[i4] = cvt4((row < KK_) ? ((const float4*)Wv)[i4] : z4);
        ((v4bfv*)Wg_b)[i4] = cvt4((row < KK_) ? ((const float4*)Wg)[i4] : z4);
    }
    // packed [W_init_h; W_init_m]  (1024 x 512)
    for (int i4 = tid0; i4 < 2 * D_ * D_ / 4; i4 += stride) {
        int row = i4 >> 7;
        float4 v = (row < D_) ? ((const float4*)W_init_h)[i4]
                              : ((const float4*)W_init_m)[i4 - D_ * (D_ / 4)];
        ((v4bfv*)Winit2_b)[i4] = cvt4(v);
    }
    for (int i4 = tid0; i4 < B_ * D_ / 4; i4 += stride)
        ((v4bfv*)Gf_b)[i4] = cvt4(((const float4*)gfeat)[i4]);
    for (int i = tid0; i < NG_; i += stride) bias_comb[i] = b_ih[i] + b_hh[i];
    for (int i = tid0; i < 2 * D_; i += stride)
        bias_init[i] = (i < D_) ? b_init_h[i] : b_init_m[i - D_];
    for (int i = tid0; i < NP_; i += stride) {
        bv_pad[i] = (i < KK_) ? bv[i] : 0.f;
        bg_pad[i] = (i < KK_) ? bg[i] : 0.f;
    }
}

// ---------------------------------------------------------------------------
// Generic bf16 MFMA GEMM, BK=64: C[M,N] = A[M,K] @ Bm[N,K]^T + bias[n]
// 128x128 tile, 4 waves, each 64x64 (4x4 of 16x16x32 MFMA).
// blockIdx.x = m-tile (fastest: consecutive blocks share B n-tile -> L2).
// OUTMODE: 0=f32, 2=logits (masked f32, n<n_real, stride out_stride),
//          3=split: n<D_ -> bf16 Cout[m*D_+n], else f32 Cout2[m*D_+n-D_]
// ---------------------------------------------------------------------------
template <int OUTMODE>
__global__ __launch_bounds__(256) void gemm_bt(
    const bf16* __restrict__ A, const bf16* __restrict__ Bm,
    const float* __restrict__ bias, void* __restrict__ Cout, void* __restrict__ Cout2,
    int M, int N, int K, int out_stride, int n_real, const int* __restrict__ lengths)
{
    __shared__ bf16 As[2 * 128 * 32];   // 16 KB
    __shared__ bf16 Bs[2 * 128 * 32];
    const int m0 = blockIdx.x * 128, n0 = blockIdx.y * 128;
    const int tid = threadIdx.x;
    const int w = tid >> 6, l = tid & 63;
    const int wm = (w >> 1) * 64, wn = (w & 1) * 64;
    const int lr = l & 15, lq = l >> 4;

    v4f acc[4][4] = {};

    for (int k0 = 0; k0 < K; k0 += 64) {
        __syncthreads();
        #pragma unroll
        for (int c = 0; c < 4; c++) {
            int u = c * 256 + tid;
            int h = u >> 9, v = u & 511;
            int row = v >> 2, kc = (v & 3) * 8;
            int u0 = c * 256 + (tid & ~63);   // wave-uniform LDS base
            GLOAD_LDS16(&A[(long)(m0 + row) * K + k0 + h * 32 + kc], &As[u0 * 8]);
            GLOAD_LDS16(&Bm[(long)(n0 + row) * K + k0 + h * 32 + kc], &Bs[u0 * 8]);
        }
        __syncthreads();
        #pragma unroll
        for (int h = 0; h < 2; h++) {
            v8bf af[4], bfv[4];
            #pragma unroll
            for (int s = 0; s < 4; s++) {
                af[s]  = *(const v8bf*)&As[h * 4096 + (wm + s * 16 + lr) * 32 + lq * 8];
                bfv[s] = *(const v8bf*)&Bs[h * 4096 + (wn + s * 16 + lr) * 32 + lq * 8];
            }
            #pragma unroll
            for (int i = 0; i < 4; i++)
                #pragma unroll
                for (int j = 0; j < 4; j++)
                    acc[i][j] = __builtin_amdgcn_mfma_f32_16x16x32_bf16(af[i], bfv[j], acc[i][j], 0, 0, 0);
        }
    }

    #pragma unroll
    for (int i = 0; i < 4; i++)
        #pragma unroll
        for (int j = 0; j < 4; j++)
            #pragma unroll
            for (int r = 0; r < 4; r++) {
                int m = m0 + wm + i * 16 + lq * 4 + r;
                int n = n0 + wn + j * 16 + lr;
                float v = acc[i][j][r];
                if (OUTMODE == 2) {
                    if (n < n_real) {
                        int t = m % T_, b = m / T_;
                        float o = (t < lengths[b]) ? (v + bias[n]) : 0.f;
                        ((float*)Cout)[(long)m * out_stride + n] = o;
                    }
                } else if (OUTMODE == 3) {
                    if (n < D_) ((bf16*)Cout)[(long)m * D_ + n] = (bf16)(v + bias[n]);
                    else ((float*)Cout2)[(long)m * D_ + n - D_] = v + bias[n];
                } else {
                    ((float*)Cout)[(long)m * out_stride + n] = v + bias[n];
                }
            }
}

// ---------------------------------------------------------------------------
// Fused LSTM recurrence, ONE launch, batch-split (rows independent given Xpre):
// 8 blocks x 512 thr (8 waves). Block owns batch rows b0..b0+15 for ALL steps.
// h tile [16 x 512] lives in LDS; m,h carry in registers; W_hh (2 MB bf16)
// streams from per-XCD L2 every step. Wave w owns d-range [w*64, w*64+64) for
// all 4 gates -> pointwise is register-local. Only __syncthreads() per step —
// no cross-block communication (grid.sync measured at ~55 us/step in R3).
// ---------------------------------------------------------------------------
__global__ __launch_bounds__(512) void lstm_fused(
    bf16* __restrict__ Hb16, const bf16* __restrict__ Whh_b,
    const float* __restrict__ Xpre, const float* __restrict__ mbuf,
    const int* __restrict__ lengths)
{
    __shared__ bf16 hbuf[16 * 512];      // 16 KB
    const int tid = threadIdx.x;
    const int w = tid >> 6, l = tid & 63;
    const int lr = l & 15, lq = l >> 4;
    const int b0 = blockIdx.x * 16;

    // h0 -> LDS (16 rows x 512)
    for (int u = tid; u < 16 * 64; u += 512)
        ((v8bf*)hbuf)[u] = *(const v8bf*)&Hb16[(long)(b0 + (u >> 6)) * D_ + (u & 63) * 8];

    // per-thread state: (b = b0+lq*4+r, d = w*64+s*16+lr)
    float m_st[4][4], h_st[4][4];
    int lenr[4];
    #pragma unroll
    for (int r = 0; r < 4; r++) {
        int b = b0 + lq * 4 + r;
        lenr[r] = lengths[b];
        #pragma unroll
        for (int s = 0; s < 4; s++) {
            int d = w * 64 + s * 16 + lr;
            m_st[r][s] = mbuf[(long)b * D_ + d];
            h_st[r][s] = (float)Hb16[(long)b * D_ + d];
        }
    }
    __syncthreads();

    for (int t = 0; t < T_; t++) {
        v4f acc[4][4] = {};   // [gate][d-subtile]
        for (int k = 0; k < 16; k++) {
            v8bf a = *(const v8bf*)&hbuf[lr * 512 + k * 32 + lq * 8];
            #pragma unroll
            for (int g = 0; g < 4; g++)
                #pragma unroll
                for (int s = 0; s < 4; s++) {
                    const bf16* bp = Whh_b +
                        (long)(g * D_ + w * 64 + s * 16 + lr) * D_ + k * 32 + lq * 8;
                    acc[g][s] = __builtin_amdgcn_mfma_f32_16x16x32_bf16(
                        a, *(const v8bf*)bp, acc[g][s], 0, 0, 0);
                }
        }
        __syncthreads();   // all A-reads of hbuf done before rewrite

        const float* xp0 = Xpre + (long)t * B_ * NG_;
        bf16* hn = Hb16 + (long)(t + 1) * B_ * D_;
        #pragma unroll
        for (int s = 0; s < 4; s++) {
            int d = w * 64 + s * 16 + lr;
            #pragma unroll
            for (int r = 0; r < 4; r++) {
                int bl = lq * 4 + r;
                int b = b0 + bl;
                const float* xp = xp0 + (long)b * NG_ + d;
                float gi = acc[0][s][r] + xp[0];
                float gf = acc[1][s][r] + xp[D_];
                float gc = acc[2][s][r] + xp[2 * D_];
                float go = acc[3][s][r] + xp[3 * D_];
                gi = 1.f / (1.f + expf(-gi));
                gf = 1.f / (1.f + expf(-gf));
                gc = tanhf(gc);
                go = 1.f / (1.f + expf(-go));
                float m_new = gf * m_st[r][s] + gi * gc;
                float h_new = go * tanhf(m_new);
                bool active = t < lenr[r];
                m_st[r][s] = active ? m_new : m_st[r][s];
                h_st[r][s] = active ? h_new : h_st[r][s];
                bf16 hv = (bf16)h_st[r][s];
                hbuf[bl * 512 + d] = hv;
                hn[(long)b * D_ + d] = hv;
            }
        }
        __syncthreads();
    }
}

// ---------------------------------------------------------------------------
// Attention + context (R2-proven). 4 waves/block share b; wave owns one t.
// ctx[b*T+t] = softmax_k(wh.tanh(Vproj+Wg h)+bh) @ spatial[b] + h_t  (bf16).
// ---------------------------------------------------------------------------
__global__ __launch_bounds__(256) void attn_kernel(
    const bf16* __restrict__ Hb16, const float* __restrict__ g_all,
    const float* __restrict__ Vproj, const float* __restrict__ wh,
    const float* __restrict__ bh_att, const float* __restrict__ spatial,
    bf16* __restrict__ ctx)
{
    const int w = threadIdx.x >> 6, l = threadIdx.x & 63;
    const int b = blockIdx.x / 5, tg = blockIdx.x % 5;
    const int t = tg * 4 + w;
    const int r = t * 128 + b;            // row in g_all
    __shared__ float sg[4][64], sal[4][64], swh[64];

    if (w == 0) swh[l] = (l < KK_) ? wh[l] : 0.f;
    sg[w][l] = (l < KK_) ? g_all[(long)r * NP_ + l] : 0.f;
    __syncthreads();

    float z = -1e30f;
    if (l < KK_) {
        const float* vp = Vproj + (long)(b * KK_ + l) * NP_;
        float a = 0.f;
        for (int j = 0; j < KK_; j++)
            a += swh[j] * tanhf(vp[j] + sg[w][j]);
        z = a + bh_att[0];
    }
    float mx = z;
    #pragma unroll
    for (int o = 32; o > 0; o >>= 1) mx = fmaxf(mx, __shfl_xor(mx, o));
    float e = (l < KK_) ? expf(z - mx) : 0.f;
    float sm = e;
    #pragma unroll
    for (int o = 32; o > 0; o >>= 1) sm += __shfl_xor(sm, o);
    sal[w][l] = e / sm;
    __syncthreads();

    const bf16* hrow = Hb16 + (long)(t + 1) * B_ * D_ + (long)b * D_;
    const float* sp = spatial + (long)b * KK_ * D_;
    bf16* crow = ctx + (long)(b * T_ + t) * D_;
    for (int d = l; d < D_; d += 64) {
        float c = 0.f;
        for (int k = 0; k < KK_; k++)
            c += sal[w][k] * sp[k * D_ + d];
        crow[d] = (bf16)(c + (float)hrow[d]);
    }
}

// ---------------------------------------------------------------------------
extern "C" void kernel_launch(void* const* d_in, const int* in_sizes, int n_in,
                              void* d_out, int out_size, void* d_ws, size_t ws_size,
                              hipStream_t stream)
{
    const float* spatial  = (const float*)d_in[0];
    const float* gfeat    = (const float*)d_in[1];
    const int*   caps     = (const int*)d_in[2];
    const int*   lengths  = (const int*)d_in[3];
    const float* emb      = (const float*)d_in[4];
    const float* W_init_h = (const float*)d_in[5];
    const float* b_init_h = (const float*)d_in[6];
    const float* W_init_m = (const float*)d_in[7];
    const float* b_init_m = (const float*)d_in[8];
    const float* W_ih     = (const float*)d_in[9];
    const float* b_ih     = (const float*)d_in[10];
    const float* W_hh     = (const float*)d_in[11];
    const float* b_hh     = (const float*)d_in[12];
    const float* Wv       = (const float*)d_in[13];
    const float* bv       = (const float*)d_in[14];
    const float* Wg       = (const float*)d_in[15];
    const float* bg       = (const float*)d_in[16];
    const float* wh       = (const float*)d_in[17];
    const float* bh_att   = (const float*)d_in[18];
    const float* Wp       = (const float*)d_in[19];
    const float* bp       = (const float*)d_in[20];
    float* out = (float*)d_out;

    char* ws = (char*)d_ws;
    size_t off = 0;
    auto alloc = [&](size_t bytes) -> void* {
        off = (off + 255) & ~(size_t)255;
        void* p = ws + off;
        off += bytes;
        return p;
    };

    bf16* Wp_b    = (bf16*)alloc((size_t)VPAD * D_ * 2);
    bf16* Whh_b   = (bf16*)alloc((size_t)NG_ * D_ * 2);
    bf16* Wih_b   = (bf16*)alloc((size_t)NG_ * XK_ * 2);
    bf16* Xin_b   = (bf16*)alloc((size_t)T_ * B_ * XK_ * 2);
    bf16* Sp_b    = (bf16*)alloc((size_t)B_ * KK_ * D_ * 2);
    bf16* Wv_b    = (bf16*)alloc((size_t)NP_ * D_ * 2);
    bf16* Wg_b    = (bf16*)alloc((size_t)NP_ * D_ * 2);
    bf16* Winit2_b= (bf16*)alloc((size_t)2 * D_ * D_ * 2);
    bf16* Gf_b    = (bf16*)alloc((size_t)B_ * D_ * 2);
    float* bias_comb = (float*)alloc(NG_ * 4);
    float* bias_init = (float*)alloc(2 * D_ * 4);
    float* bv_pad    = (float*)alloc(NP_ * 4);
    float* bg_pad    = (float*)alloc(NP_ * 4);
    bf16* Hb16    = (bf16*)alloc((size_t)(T_ + 1) * B_ * D_ * 2);
    float* mbuf   = (float*)alloc((size_t)B_ * D_ * 4);
    float* Xpre   = (float*)alloc((size_t)T_ * B_ * NG_ * 4);
    float* VprojW = (float*)alloc((size_t)B_ * KK_ * NP_ * 4);
    float* g_allW = (float*)alloc((size_t)T_ * B_ * NP_ * 4);
    bf16* ctx     = (bf16*)alloc((size_t)T_ * B_ * D_ * 2);

    // 1. prep / conversions
    prep_kernel<<<1024, 256, 0, stream>>>(
        spatial, gfeat, caps, emb, W_init_h, b_init_h, W_init_m, b_init_m,
        W_ih, b_ih, W_hh, b_hh, Wv, bv, Wg, bg, Wp,
        Wp_b, Whh_b, Wih_b, Xin_b, Sp_b, Wv_b, Wg_b, Winit2_b, Gf_b,
        bias_comb, bias_init, bv_pad, bg_pad);

    // 2. h0 (bf16 -> Hb16[0]) and m0 (f32 -> mbuf) in one GEMM
    gemm_bt<3><<<dim3(1, 8), 256, 0, stream>>>(Gf_b, Winit2_b, bias_init,
                                               Hb16, mbuf, B_, 2 * D_, D_, 0, 0, nullptr);

    // 3. V_proj = spatial @ Wv^T + bv  -> [B*K, 128] f32
    gemm_bt<0><<<dim3((B_ * KK_) / 128, 1), 256, 0, stream>>>(
        Sp_b, Wv_b, bv_pad, VprojW, nullptr, B_ * KK_, NP_, D_, NP_, 0, nullptr);

    // 4. Xpre = Xin @ W_ih^T + (b_ih + b_hh)  -> [T*B, 2048] f32
    gemm_bt<0><<<dim3((T_ * B_) / 128, NG_ / 128), 256, 0, stream>>>(
        Xin_b, Wih_b, bias_comb, Xpre, nullptr, T_ * B_, NG_, XK_, NG_, 0, nullptr);

    // 5. all 20 LSTM steps in ONE launch (batch-split, no cross-block deps)
    lstm_fused<<<8, 512, 0, stream>>>(Hb16, Whh_b, Xpre, mbuf, lengths);

    // 6. g_all = H[1..T] @ Wg^T + bg  -> [T*B, 128] f32
    gemm_bt<0><<<dim3((T_ * B_) / 128, 1), 256, 0, stream>>>(
        Hb16 + (size_t)B_ * D_, Wg_b, bg_pad, g_allW, nullptr, T_ * B_, NP_, D_, NP_, 0, nullptr);

    // 7. attention + ctx = c + h  (bf16, rows b*T+t)
    attn_kernel<<<B_ * 5, 256, 0, stream>>>(Hb16, g_allW, VprojW, wh, bh_att,
                                            spatial, ctx);

    // 8. logits = ctx @ Wp^T + bp, masked, -> d_out [B*T, V]
    gemm_bt<2><<<dim3((T_ * B_) / 128, VPAD / 128), 256, 0, stream>>>(
        ctx, Wp_b, bp, out, nullptr, T_ * B_, VPAD, D_, V_, V_, lengths);
}

// Round 6
// 545.311 us; speedup vs baseline: 3.0837x; 3.0837x over previous
//
#include <hip/hip_runtime.h>
#include <hip/hip_bf16.h>
#include <math.h>

typedef __bf16 bf16;
typedef __bf16 v8bf __attribute__((ext_vector_type(8)));
typedef __bf16 v4bfv __attribute__((ext_vector_type(4)));
typedef float  v4f  __attribute__((ext_vector_type(4)));

#define B_   128
#define KK_  49
#define D_   512
#define E_   256
#define V_   10000
#define T_   20
#define NG_  2048   // 4*D
#define XK_  768    // E+D
#define VPAD 10112  // 79*128 (Wp rows padded)
#define NP_  128    // padded small-N
#define NBLK 64     // lstm_persist grid

#define GLOAD_LDS16(gp, lp) \
    __builtin_amdgcn_global_load_lds((const __attribute__((address_space(1))) void*)(gp), \
                                     (__attribute__((address_space(3))) void*)(lp), 16, 0, 0)

__device__ inline v4bfv cvt4(float4 v) {
    v4bfv o; o[0] = (bf16)v.x; o[1] = (bf16)v.y; o[2] = (bf16)v.z; o[3] = (bf16)v.w;
    return o;
}

// ---------------------------------------------------------------------------
// Prep: fp32->bf16 conversions, padding, gather of LSTM input rows, packed
// init weights/biases, barrier-flag zeroing.
// ---------------------------------------------------------------------------
__global__ void prep_kernel(
    const float* __restrict__ spatial, const float* __restrict__ gfeat,
    const int* __restrict__ caps, const float* __restrict__ emb,
    const float* __restrict__ W_init_h, const float* __restrict__ b_init_h,
    const float* __restrict__ W_init_m, const float* __restrict__ b_init_m,
    const float* __restrict__ W_ih, const float* __restrict__ b_ih,
    const float* __restrict__ W_hh, const float* __restrict__ b_hh,
    const float* __restrict__ Wv, const float* __restrict__ bv,
    const float* __restrict__ Wg, const float* __restrict__ bg,
    const float* __restrict__ Wp,
    bf16* __restrict__ Wp_b, bf16* __restrict__ Whh_b, bf16* __restrict__ Wih_b,
    bf16* __restrict__ Xin_b, bf16* __restrict__ Sp_b,
    bf16* __restrict__ Wv_b, bf16* __restrict__ Wg_b,
    bf16* __restrict__ Winit2_b, bf16* __restrict__ Gf_b,
    float* __restrict__ bias_comb, float* __restrict__ bias_init,
    float* __restrict__ bv_pad, float* __restrict__ bg_pad,
    int* __restrict__ flags)
{
    const int stride = gridDim.x * blockDim.x;
    const int tid0 = blockIdx.x * blockDim.x + threadIdx.x;
    const float4 z4 = make_float4(0.f, 0.f, 0.f, 0.f);

    for (int i = tid0; i < NBLK * 32; i += stride) flags[i] = 0;

    for (int i4 = tid0; i4 < VPAD * D_ / 4; i4 += stride) {
        int row = i4 >> 7;
        float4 v = (row < V_) ? ((const float4*)Wp)[i4] : z4;
        ((v4bfv*)Wp_b)[i4] = cvt4(v);
    }
    for (int i4 = tid0; i4 < NG_ * D_ / 4; i4 += stride)
        ((v4bfv*)Whh_b)[i4] = cvt4(((const float4*)W_hh)[i4]);
    for (int i4 = tid0; i4 < NG_ * XK_ / 4; i4 += stride)
        ((v4bfv*)Wih_b)[i4] = cvt4(((const float4*)W_ih)[i4]);
    // Xin rows r = t*128+b : [emb[captions[b,t]], global_feats[b]]
    for (int i4 = tid0; i4 < T_ * B_ * XK_ / 4; i4 += stride) {
        int r = i4 / (XK_ / 4), c4 = i4 - r * (XK_ / 4);
        int c = c4 * 4;
        int t = r >> 7, b = r & 127;
        float4 v;
        if (c < E_) v = *(const float4*)&emb[(long)caps[b * T_ + t] * E_ + c];
        else        v = *(const float4*)&gfeat[(long)b * D_ + (c - E_)];
        ((v4bfv*)Xin_b)[i4] = cvt4(v);
    }
    for (int i4 = tid0; i4 < B_ * KK_ * D_ / 4; i4 += stride)
        ((v4bfv*)Sp_b)[i4] = cvt4(((const float4*)spatial)[i4]);
    for (int i4 = tid0; i4 < NP_ * D_ / 4; i4 += stride) {
        int row = i4 >> 7;
        ((v4bfv*)Wv_b)[i4] = cvt4((row < KK_) ? ((const float4*)Wv)[i4] : z4);
        ((v4bfv*)Wg_b)[i4] = cvt4((row < KK_) ? ((const float4*)Wg)[i4] : z4);
    }
    // packed [W_init_h; W_init_m]  (1024 x 512)
    for (int i4 = tid0; i4 < 2 * D_ * D_ / 4; i4 += stride) {
        int row = i4 >> 7;
        float4 v = (row < D_) ? ((const float4*)W_init_h)[i4]
                              : ((const float4*)W_init_m)[i4 - D_ * (D_ / 4)];
        ((v4bfv*)Winit2_b)[i4] = cvt4(v);
    }
    for (int i4 = tid0; i4 < B_ * D_ / 4; i4 += stride)
        ((v4bfv*)Gf_b)[i4] = cvt4(((const float4*)gfeat)[i4]);
    for (int i = tid0; i < NG_; i += stride) bias_comb[i] = b_ih[i] + b_hh[i];
    for (int i = tid0; i < 2 * D_; i += stride)
        bias_init[i] = (i < D_) ? b_init_h[i] : b_init_m[i - D_];
    for (int i = tid0; i < NP_; i += stride) {
        bv_pad[i] = (i < KK_) ? bv[i] : 0.f;
        bg_pad[i] = (i < KK_) ? bg[i] : 0.f;
    }
}

// ---------------------------------------------------------------------------
// Generic bf16 MFMA GEMM, BK=64: C[M,N] = A[M,K] @ Bm[N,K]^T + bias[n]
// 128x128 tile, 4 waves, each 64x64. blockIdx.x = m-tile (fastest).
// OUTMODE: 0=f32, 2=logits (masked f32, n<n_real, stride out_stride),
//          3=split: n<D_ -> bf16 Cout[m*D_+n], else f32 Cout2[m*D_+n-D_]
// ---------------------------------------------------------------------------
template <int OUTMODE>
__global__ __launch_bounds__(256) void gemm_bt(
    const bf16* __restrict__ A, const bf16* __restrict__ Bm,
    const float* __restrict__ bias, void* __restrict__ Cout, void* __restrict__ Cout2,
    int M, int N, int K, int out_stride, int n_real, const int* __restrict__ lengths)
{
    __shared__ bf16 As[2 * 128 * 32];
    __shared__ bf16 Bs[2 * 128 * 32];
    const int m0 = blockIdx.x * 128, n0 = blockIdx.y * 128;
    const int tid = threadIdx.x;
    const int w = tid >> 6, l = tid & 63;
    const int wm = (w >> 1) * 64, wn = (w & 1) * 64;
    const int lr = l & 15, lq = l >> 4;

    v4f acc[4][4] = {};

    for (int k0 = 0; k0 < K; k0 += 64) {
        __syncthreads();
        #pragma unroll
        for (int c = 0; c < 4; c++) {
            int u = c * 256 + tid;
            int h = u >> 9, v = u & 511;
            int row = v >> 2, kc = (v & 3) * 8;
            int u0 = c * 256 + (tid & ~63);
            GLOAD_LDS16(&A[(long)(m0 + row) * K + k0 + h * 32 + kc], &As[u0 * 8]);
            GLOAD_LDS16(&Bm[(long)(n0 + row) * K + k0 + h * 32 + kc], &Bs[u0 * 8]);
        }
        __syncthreads();
        #pragma unroll
        for (int h = 0; h < 2; h++) {
            v8bf af[4], bfv[4];
            #pragma unroll
            for (int s = 0; s < 4; s++) {
                af[s]  = *(const v8bf*)&As[h * 4096 + (wm + s * 16 + lr) * 32 + lq * 8];
                bfv[s] = *(const v8bf*)&Bs[h * 4096 + (wn + s * 16 + lr) * 32 + lq * 8];
            }
            #pragma unroll
            for (int i = 0; i < 4; i++)
                #pragma unroll
                for (int j = 0; j < 4; j++)
                    acc[i][j] = __builtin_amdgcn_mfma_f32_16x16x32_bf16(af[i], bfv[j], acc[i][j], 0, 0, 0);
        }
    }

    #pragma unroll
    for (int i = 0; i < 4; i++)
        #pragma unroll
        for (int j = 0; j < 4; j++)
            #pragma unroll
            for (int r = 0; r < 4; r++) {
                int m = m0 + wm + i * 16 + lq * 4 + r;
                int n = n0 + wn + j * 16 + lr;
                float v = acc[i][j][r];
                if (OUTMODE == 2) {
                    if (n < n_real) {
                        int t = m % T_, b = m / T_;
                        float o = (t < lengths[b]) ? (v + bias[n]) : 0.f;
                        ((float*)Cout)[(long)m * out_stride + n] = o;
                    }
                } else if (OUTMODE == 3) {
                    if (n < D_) ((bf16*)Cout)[(long)m * D_ + n] = (bf16)(v + bias[n]);
                    else ((float*)Cout2)[(long)m * D_ + n - D_] = v + bias[n];
                } else {
                    ((float*)Cout)[(long)m * out_stride + n] = v + bias[n];
                }
            }
}

// ---------------------------------------------------------------------------
// Persistent LSTM recurrence: ONE cooperative launch, all T steps.
// 64 blocks x 256 thr: block = (bt in 0..1: 64 batch rows) x (dt in 0..31:
// 16 d-cols, all 4 gates). W_hh slice (4g x 16d x 512, padded) lives in LDS
// for ALL steps. Thread owns (4 b) x (1 d) x (all 4 gates) -> pointwise is
// register-local; m/h state in registers. Cross-block h-exchange per step via
// flag-array barrier: each block release-stores its own padded flag; wave 0
// polls all 64 flags (one per lane) — no serialized RMW (R3's 55 us/step was
// 256 atomics on ONE line). Xpre[t+1] prefetched between flag-set and poll.
// ---------------------------------------------------------------------------
__global__ __launch_bounds__(256) void lstm_persist(
    bf16* __restrict__ Hb16, const bf16* __restrict__ Whh_b,
    const float* __restrict__ Xpre, const float* __restrict__ mbuf,
    const int* __restrict__ lengths, int* __restrict__ flags)
{
    const int tid = threadIdx.x;
    const int w = tid >> 6, l = tid & 63;
    const int lr = l & 15, lq = l >> 4;
    const int bt = blockIdx.x & 1, dt = blockIdx.x >> 1;
    const int b0 = bt * 64, d0 = dt * 16;

    __shared__ bf16 Bl[64][520];   // 67 KB, +8 pad -> 2-way-free LDS banks

    // one-time stage of W_hh slice: row (g*16+dd) <- global row g*512+d0+dd
    for (int u = tid; u < 64 * 64; u += 256) {
        int row = u >> 6, kc = (u & 63) * 8;
        int g = row >> 4, dd = row & 15;
        *(v8bf*)&Bl[row][kc] = *(const v8bf*)&Whh_b[(long)(g * D_ + d0 + dd) * D_ + kc];
    }

    // per-thread state: r=0..3 -> b = b0 + w*16 + lq*4 + r ; d = d0 + lr
    const int d = d0 + lr;
    float m_st[4], h_st[4];
    float xpf[4][4];
    int lenr[4];
    #pragma unroll
    for (int r = 0; r < 4; r++) {
        int b = b0 + w * 16 + lq * 4 + r;
        lenr[r] = lengths[b];
        m_st[r] = mbuf[(long)b * D_ + d];
        h_st[r] = (float)Hb16[(long)b * D_ + d];
        #pragma unroll
        for (int g = 0; g < 4; g++)
            xpf[r][g] = Xpre[(long)b * NG_ + g * D_ + d];
    }
    __syncthreads();

    for (int t = 0; t < T_; t++) {
        // gates = H[t] @ Whh^T : wave w owns m-rows b0+w*16..+15, 4 gate tiles
        const bf16* Arow = Hb16 + (long)t * B_ * D_ + (long)(b0 + w * 16 + lr) * D_;
        v4f acc[4] = {};
        #pragma unroll
        for (int kk = 0; kk < 16; kk++) {
            v8bf a = *(const v8bf*)&Arow[kk * 32 + lq * 8];
            #pragma unroll
            for (int g = 0; g < 4; g++) {
                v8bf bv = *(const v8bf*)&Bl[g * 16 + lr][kk * 32 + lq * 8];
                acc[g] = __builtin_amdgcn_mfma_f32_16x16x32_bf16(a, bv, acc[g], 0, 0, 0);
            }
        }

        bf16* hn = Hb16 + (long)(t + 1) * B_ * D_;
        #pragma unroll
        for (int r = 0; r < 4; r++) {
            int b = b0 + w * 16 + lq * 4 + r;
            float gi = acc[0][r] + xpf[r][0];
            float gf = acc[1][r] + xpf[r][1];
            float gc = acc[2][r] + xpf[r][2];
            float go = acc[3][r] + xpf[r][3];
            gi = 1.f / (1.f + expf(-gi));
            gf = 1.f / (1.f + expf(-gf));
            gc = tanhf(gc);
            go = 1.f / (1.f + expf(-go));
            float m_new = gf * m_st[r] + gi * gc;
            float h_new = go * tanhf(m_new);
            bool active = t < lenr[r];
            m_st[r] = active ? m_new : m_st[r];
            h_st[r] = active ? h_new : h_st[r];
            hn[(long)b * D_ + d] = (bf16)h_st[r];
        }

        if (t + 1 < T_) {
            __syncthreads();               // drains each wave's stores (vmcnt0)
            if (tid == 0) {
                __threadfence();           // release h-writes device-wide
                __hip_atomic_store(&flags[blockIdx.x * 32], t + 1,
                                   __ATOMIC_RELAXED, __HIP_MEMORY_SCOPE_AGENT);
            }
            // prefetch next step's Xpre while other blocks arrive
            #pragma unroll
            for (int r = 0; r < 4; r++) {
                int b = b0 + w * 16 + lq * 4 + r;
                #pragma unroll
                for (int g = 0; g < 4; g++)
                    xpf[r][g] = Xpre[(long)(t + 1) * B_ * NG_ + (long)b * NG_ + g * D_ + d];
            }
            if (w == 0) {                  // lane i polls block i's flag
                int need = t + 1, v;
                do {
                    v = __hip_atomic_load(&flags[l * 32], __ATOMIC_RELAXED,
                                          __HIP_MEMORY_SCOPE_AGENT);
                } while (__any(v < need));
                __threadfence();           // acquire (invalidates CU L1 / XCD L2)
            }
            __syncthreads();
        }
    }
}

// ---------------------------------------------------------------------------
// Attention + context. 4 waves/block share b (Vproj tile staged in LDS once);
// wave owns one t. z via LDS-only inner loop; c via v8bf-vectorized k-loop.
// ctx[b*T+t] = softmax_k(wh.tanh(Vproj+Wg h))@spatial[b] + h_t  (bf16).
// (bh_att dropped: softmax is shift-invariant.)
// ---------------------------------------------------------------------------
__global__ __launch_bounds__(256) void attn_kernel(
    const bf16* __restrict__ Hb16, const float* __restrict__ g_all,
    const float* __restrict__ Vproj, const float* __restrict__ wh,
    const bf16* __restrict__ Sp_b, bf16* __restrict__ ctx)
{
    const int w = threadIdx.x >> 6, l = threadIdx.x & 63;
    const int b = blockIdx.x / 5, tg = blockIdx.x % 5;
    const int t = tg * 4 + w;
    const int r = t * 128 + b;
    __shared__ float svp[KK_][53];        // 10.4 KB, stride 53 (coprime w/ 32)
    __shared__ float sg[4][64], sal[4][64], swh[64];

    // stage Vproj[b] 49x49 tile (shared by all 4 waves)
    for (int p = threadIdx.x; p < KK_ * 64; p += 256) {
        int k = p >> 6, j = p & 63;
        if (j < KK_) svp[k][j] = Vproj[((long)b * KK_ + k) * NP_ + j];
    }
    if (w == 0) swh[l] = (l < KK_) ? wh[l] : 0.f;
    sg[w][l] = (l < KK_) ? g_all[(long)r * NP_ + l] : 0.f;
    __syncthreads();

    float z = -1e30f;
    if (l < KK_) {
        float a = 0.f;
        for (int j = 0; j < KK_; j++)
            a += swh[j] * tanhf(svp[l][j] + sg[w][j]);
        z = a;
    }
    float mx = z;
    #pragma unroll
    for (int o = 32; o > 0; o >>= 1) mx = fmaxf(mx, __shfl_xor(mx, o));
    float e = (l < KK_) ? expf(z - mx) : 0.f;
    float sm = e;
    #pragma unroll
    for (int o = 32; o > 0; o >>= 1) sm += __shfl_xor(sm, o);
    sal[w][l] = e / sm;
    __syncthreads();

    // c[d-range l*8..l*8+7] = sum_k alpha[k] * spatial[b,k,:] ; + h_t
    const bf16* hrow = Hb16 + (long)(t + 1) * B_ * D_ + (long)b * D_;
    const bf16* sp = Sp_b + (long)b * KK_ * D_;
    bf16* crow = ctx + (long)(b * T_ + t) * D_;
    v8bf hro = *(const v8bf*)&hrow[l * 8];
    float c[8] = {};
    for (int k = 0; k < KK_; k++) {
        v8bf s8 = *(const v8bf*)&sp[k * D_ + l * 8];
        float al = sal[w][k];
        #pragma unroll
        for (int e2 = 0; e2 < 8; e2++) c[e2] += al * (float)s8[e2];
    }
    v8bf outv;
    #pragma unroll
    for (int e2 = 0; e2 < 8; e2++) outv[e2] = (bf16)(c[e2] + (float)hro[e2]);
    *(v8bf*)&crow[l * 8] = outv;
}

// ---------------------------------------------------------------------------
extern "C" void kernel_launch(void* const* d_in, const int* in_sizes, int n_in,
                              void* d_out, int out_size, void* d_ws, size_t ws_size,
                              hipStream_t stream)
{
    const float* spatial  = (const float*)d_in[0];
    const float* gfeat    = (const float*)d_in[1];
    const int*   caps     = (const int*)d_in[2];
    const int*   lengths  = (const int*)d_in[3];
    const float* emb      = (const float*)d_in[4];
    const float* W_init_h = (const float*)d_in[5];
    const float* b_init_h = (const float*)d_in[6];
    const float* W_init_m = (const float*)d_in[7];
    const float* b_init_m = (const float*)d_in[8];
    const float* W_ih     = (const float*)d_in[9];
    const float* b_ih     = (const float*)d_in[10];
    const float* W_hh     = (const float*)d_in[11];
    const float* b_hh     = (const float*)d_in[12];
    const float* Wv       = (const float*)d_in[13];
    const float* bv       = (const float*)d_in[14];
    const float* Wg       = (const float*)d_in[15];
    const float* bg       = (const float*)d_in[16];
    const float* wh       = (const float*)d_in[17];
    const float* bh_att   = (const float*)d_in[18];
    const float* Wp       = (const float*)d_in[19];
    const float* bp       = (const float*)d_in[20];
    float* out = (float*)d_out;
    (void)bh_att;

    char* ws = (char*)d_ws;
    size_t off = 0;
    auto alloc = [&](size_t bytes) -> void* {
        off = (off + 255) & ~(size_t)255;
        void* p = ws + off;
        off += bytes;
        return p;
    };

    bf16* Wp_b    = (bf16*)alloc((size_t)VPAD * D_ * 2);
    bf16* Whh_b   = (bf16*)alloc((size_t)NG_ * D_ * 2);
    bf16* Wih_b   = (bf16*)alloc((size_t)NG_ * XK_ * 2);
    bf16* Xin_b   = (bf16*)alloc((size_t)T_ * B_ * XK_ * 2);
    bf16* Sp_b    = (bf16*)alloc((size_t)B_ * KK_ * D_ * 2);
    bf16* Wv_b    = (bf16*)alloc((size_t)NP_ * D_ * 2);
    bf16* Wg_b    = (bf16*)alloc((size_t)NP_ * D_ * 2);
    bf16* Winit2_b= (bf16*)alloc((size_t)2 * D_ * D_ * 2);
    bf16* Gf_b    = (bf16*)alloc((size_t)B_ * D_ * 2);
    float* bias_comb = (float*)alloc(NG_ * 4);
    float* bias_init = (float*)alloc(2 * D_ * 4);
    float* bv_pad    = (float*)alloc(NP_ * 4);
    float* bg_pad    = (float*)alloc(NP_ * 4);
    bf16* Hb16    = (bf16*)alloc((size_t)(T_ + 1) * B_ * D_ * 2);
    float* mbuf   = (float*)alloc((size_t)B_ * D_ * 4);
    float* Xpre   = (float*)alloc((size_t)T_ * B_ * NG_ * 4);
    float* VprojW = (float*)alloc((size_t)B_ * KK_ * NP_ * 4);
    float* g_allW = (float*)alloc((size_t)T_ * B_ * NP_ * 4);
    bf16* ctx     = (bf16*)alloc((size_t)T_ * B_ * D_ * 2);
    int*  flags   = (int*)alloc((size_t)NBLK * 32 * 4);

    // 1. prep / conversions / flag zeroing
    prep_kernel<<<1024, 256, 0, stream>>>(
        spatial, gfeat, caps, emb, W_init_h, b_init_h, W_init_m, b_init_m,
        W_ih, b_ih, W_hh, b_hh, Wv, bv, Wg, bg, Wp,
        Wp_b, Whh_b, Wih_b, Xin_b, Sp_b, Wv_b, Wg_b, Winit2_b, Gf_b,
        bias_comb, bias_init, bv_pad, bg_pad, flags);

    // 2. h0 (bf16 -> Hb16[0]) and m0 (f32 -> mbuf) in one GEMM
    gemm_bt<3><<<dim3(1, 8), 256, 0, stream>>>(Gf_b, Winit2_b, bias_init,
                                               Hb16, mbuf, B_, 2 * D_, D_, 0, 0, nullptr);

    // 3. V_proj = spatial @ Wv^T + bv  -> [B*K, 128] f32
    gemm_bt<0><<<dim3((B_ * KK_) / 128, 1), 256, 0, stream>>>(
        Sp_b, Wv_b, bv_pad, VprojW, nullptr, B_ * KK_, NP_, D_, NP_, 0, nullptr);

    // 4. Xpre = Xin @ W_ih^T + (b_ih + b_hh)  -> [T*B, 2048] f32
    gemm_bt<0><<<dim3((T_ * B_) / 128, NG_ / 128), 256, 0, stream>>>(
        Xin_b, Wih_b, bias_comb, Xpre, nullptr, T_ * B_, NG_, XK_, NG_, 0, nullptr);

    // 5. all 20 LSTM steps: ONE cooperative persistent kernel, flag barrier
    {
        void* args[] = { (void*)&Hb16, (void*)&Whh_b, (void*)&Xpre,
                         (void*)&mbuf, (void*)&lengths, (void*)&flags };
        hipLaunchCooperativeKernel((void*)lstm_persist, dim3(NBLK), dim3(256),
                                   args, 0, stream);
    }

    // 6. g_all = H[1..T] @ Wg^T + bg  -> [T*B, 128] f32
    gemm_bt<0><<<dim3((T_ * B_) / 128, 1), 256, 0, stream>>>(
        Hb16 + (size_t)B_ * D_, Wg_b, bg_pad, g_allW, nullptr, T_ * B_, NP_, D_, NP_, 0, nullptr);

    // 7. attention + ctx = c + h  (bf16, rows b*T+t)
    attn_kernel<<<B_ * 5, 256, 0, stream>>>(Hb16, g_allW, VprojW, wh, Sp_b, ctx);

    // 8. logits = ctx @ Wp^T + bp, masked, -> d_out [B*T, V]
    gemm_bt<2><<<dim3((T_ * B_) / 128, VPAD / 128), 256, 0, stream>>>(
        ctx, Wp_b, bp, out, nullptr, T_ * B_, VPAD, D_, V_, V_, lengths);
}

// Round 7
// 473.531 us; speedup vs baseline: 3.5511x; 1.1516x over previous
//
#include <hip/hip_runtime.h>
#include <hip/hip_bf16.h>
#include <math.h>

typedef __bf16 bf16;
typedef __bf16 v8bf __attribute__((ext_vector_type(8)));
typedef __bf16 v4bfv __attribute__((ext_vector_type(4)));
typedef float  v4f  __attribute__((ext_vector_type(4)));

#define B_   128
#define KK_  49
#define D_   512
#define E_   256
#define V_   10000
#define T_   20
#define NG_  2048   // 4*D
#define XK_  768    // E+D
#define VPAD 10112  // 79*128 (Wp rows padded)
#define NP_  128    // padded small-N
#define NBLK 64     // lstm_persist grid

#define GLOAD_LDS16(gp, lp) \
    __builtin_amdgcn_global_load_lds((const __attribute__((address_space(1))) void*)(gp), \
                                     (__attribute__((address_space(3))) void*)(lp), 16, 0, 0)

__device__ inline v4bfv cvt4(float4 v) {
    v4bfv o; o[0] = (bf16)v.x; o[1] = (bf16)v.y; o[2] = (bf16)v.z; o[3] = (bf16)v.w;
    return o;
}

// ---------------------------------------------------------------------------
// Prep: fp32->bf16 conversions, padding, gather of LSTM input rows, packed
// init weights/biases, barrier-flag zeroing.
// ---------------------------------------------------------------------------
__global__ void prep_kernel(
    const float* __restrict__ spatial, const float* __restrict__ gfeat,
    const int* __restrict__ caps, const float* __restrict__ emb,
    const float* __restrict__ W_init_h, const float* __restrict__ b_init_h,
    const float* __restrict__ W_init_m, const float* __restrict__ b_init_m,
    const float* __restrict__ W_ih, const float* __restrict__ b_ih,
    const float* __restrict__ W_hh, const float* __restrict__ b_hh,
    const float* __restrict__ Wv, const float* __restrict__ bv,
    const float* __restrict__ Wg, const float* __restrict__ bg,
    const float* __restrict__ Wp,
    bf16* __restrict__ Wp_b, bf16* __restrict__ Whh_b, bf16* __restrict__ Wih_b,
    bf16* __restrict__ Xin_b, bf16* __restrict__ Sp_b,
    bf16* __restrict__ Wv_b, bf16* __restrict__ Wg_b,
    bf16* __restrict__ Winit2_b, bf16* __restrict__ Gf_b,
    float* __restrict__ bias_comb, float* __restrict__ bias_init,
    float* __restrict__ bv_pad, float* __restrict__ bg_pad,
    int* __restrict__ flags)
{
    const int stride = gridDim.x * blockDim.x;
    const int tid0 = blockIdx.x * blockDim.x + threadIdx.x;
    const float4 z4 = make_float4(0.f, 0.f, 0.f, 0.f);

    for (int i = tid0; i < NBLK * 32; i += stride) flags[i] = 0;

    for (int i4 = tid0; i4 < VPAD * D_ / 4; i4 += stride) {
        int row = i4 >> 7;
        float4 v = (row < V_) ? ((const float4*)Wp)[i4] : z4;
        ((v4bfv*)Wp_b)[i4] = cvt4(v);
    }
    for (int i4 = tid0; i4 < NG_ * D_ / 4; i4 += stride)
        ((v4bfv*)Whh_b)[i4] = cvt4(((const float4*)W_hh)[i4]);
    for (int i4 = tid0; i4 < NG_ * XK_ / 4; i4 += stride)
        ((v4bfv*)Wih_b)[i4] = cvt4(((const float4*)W_ih)[i4]);
    // Xin rows r = t*128+b : [emb[captions[b,t]], global_feats[b]]
    for (int i4 = tid0; i4 < T_ * B_ * XK_ / 4; i4 += stride) {
        int r = i4 / (XK_ / 4), c4 = i4 - r * (XK_ / 4);
        int c = c4 * 4;
        int t = r >> 7, b = r & 127;
        float4 v;
        if (c < E_) v = *(const float4*)&emb[(long)caps[b * T_ + t] * E_ + c];
        else        v = *(const float4*)&gfeat[(long)b * D_ + (c - E_)];
        ((v4bfv*)Xin_b)[i4] = cvt4(v);
    }
    for (int i4 = tid0; i4 < B_ * KK_ * D_ / 4; i4 += stride)
        ((v4bfv*)Sp_b)[i4] = cvt4(((const float4*)spatial)[i4]);
    for (int i4 = tid0; i4 < NP_ * D_ / 4; i4 += stride) {
        int row = i4 >> 7;
        ((v4bfv*)Wv_b)[i4] = cvt4((row < KK_) ? ((const float4*)Wv)[i4] : z4);
        ((v4bfv*)Wg_b)[i4] = cvt4((row < KK_) ? ((const float4*)Wg)[i4] : z4);
    }
    // packed [W_init_h; W_init_m]  (1024 x 512)
    for (int i4 = tid0; i4 < 2 * D_ * D_ / 4; i4 += stride) {
        int row = i4 >> 7;
        float4 v = (row < D_) ? ((const float4*)W_init_h)[i4]
                              : ((const float4*)W_init_m)[i4 - D_ * (D_ / 4)];
        ((v4bfv*)Winit2_b)[i4] = cvt4(v);
    }
    for (int i4 = tid0; i4 < B_ * D_ / 4; i4 += stride)
        ((v4bfv*)Gf_b)[i4] = cvt4(((const float4*)gfeat)[i4]);
    for (int i = tid0; i < NG_; i += stride) bias_comb[i] = b_ih[i] + b_hh[i];
    for (int i = tid0; i < 2 * D_; i += stride)
        bias_init[i] = (i < D_) ? b_init_h[i] : b_init_m[i - D_];
    for (int i = tid0; i < NP_; i += stride) {
        bv_pad[i] = (i < KK_) ? bv[i] : 0.f;
        bg_pad[i] = (i < KK_) ? bg[i] : 0.f;
    }
}

// ---------------------------------------------------------------------------
// Generic bf16 MFMA GEMM, BK=64: C[M,N] = A[M,K] @ Bm[N,K]^T + bias[n]
// 128x128 tile, 4 waves, each 64x64. blockIdx.x = m-tile (fastest).
// __launch_bounds__(256,4): request 4 blocks/CU (VGPR<=128; now 72).
// OUTMODE: 0=f32, 2=logits (masked f32, n<n_real, stride out_stride),
//          3=split: n<D_ -> bf16 Cout[m*D_+n], else f32 Cout2[m*D_+n-D_]
// ---------------------------------------------------------------------------
template <int OUTMODE>
__global__ __launch_bounds__(256, 4) void gemm_bt(
    const bf16* __restrict__ A, const bf16* __restrict__ Bm,
    const float* __restrict__ bias, void* __restrict__ Cout, void* __restrict__ Cout2,
    int M, int N, int K, int out_stride, int n_real, const int* __restrict__ lengths)
{
    __shared__ bf16 As[2 * 128 * 32];
    __shared__ bf16 Bs[2 * 128 * 32];
    const int m0 = blockIdx.x * 128, n0 = blockIdx.y * 128;
    const int tid = threadIdx.x;
    const int w = tid >> 6, l = tid & 63;
    const int wm = (w >> 1) * 64, wn = (w & 1) * 64;
    const int lr = l & 15, lq = l >> 4;

    v4f acc[4][4] = {};

    for (int k0 = 0; k0 < K; k0 += 64) {
        __syncthreads();
        #pragma unroll
        for (int c = 0; c < 4; c++) {
            int u = c * 256 + tid;
            int h = u >> 9, v = u & 511;
            int row = v >> 2, kc = (v & 3) * 8;
            int u0 = c * 256 + (tid & ~63);
            GLOAD_LDS16(&A[(long)(m0 + row) * K + k0 + h * 32 + kc], &As[u0 * 8]);
            GLOAD_LDS16(&Bm[(long)(n0 + row) * K + k0 + h * 32 + kc], &Bs[u0 * 8]);
        }
        __syncthreads();
        #pragma unroll
        for (int h = 0; h < 2; h++) {
            v8bf af[4], bfv[4];
            #pragma unroll
            for (int s = 0; s < 4; s++) {
                af[s]  = *(const v8bf*)&As[h * 4096 + (wm + s * 16 + lr) * 32 + lq * 8];
                bfv[s] = *(const v8bf*)&Bs[h * 4096 + (wn + s * 16 + lr) * 32 + lq * 8];
            }
            #pragma unroll
            for (int i = 0; i < 4; i++)
                #pragma unroll
                for (int j = 0; j < 4; j++)
                    acc[i][j] = __builtin_amdgcn_mfma_f32_16x16x32_bf16(af[i], bfv[j], acc[i][j], 0, 0, 0);
        }
    }

    #pragma unroll
    for (int i = 0; i < 4; i++)
        #pragma unroll
        for (int j = 0; j < 4; j++)
            #pragma unroll
            for (int r = 0; r < 4; r++) {
                int m = m0 + wm + i * 16 + lq * 4 + r;
                int n = n0 + wn + j * 16 + lr;
                float v = acc[i][j][r];
                if (OUTMODE == 2) {
                    if (n < n_real) {
                        int t = m % T_, b = m / T_;
                        float o = (t < lengths[b]) ? (v + bias[n]) : 0.f;
                        ((float*)Cout)[(long)m * out_stride + n] = o;
                    }
                } else if (OUTMODE == 3) {
                    if (n < D_) ((bf16*)Cout)[(long)m * D_ + n] = (bf16)(v + bias[n]);
                    else ((float*)Cout2)[(long)m * D_ + n - D_] = v + bias[n];
                } else {
                    ((float*)Cout)[(long)m * out_stride + n] = v + bias[n];
                }
            }
}

// ---------------------------------------------------------------------------
// Persistent LSTM recurrence: ONE REGULAR launch, all T steps.
// 64 blocks x 256 thr: block = (bt in 0..1: 64 batch rows) x (dt in 0..31:
// 16 d-cols, all 4 gates). Co-residency by capacity: 64 blocks, 66.5 KB LDS
// -> 1 block/CU on a 256-CU chip; no cooperative launch needed (R6 showed
// hipLaunchCooperativeKernel adds large graph-replay overhead).
// W_hh slice in LDS for ALL steps; m/h in registers; gates land in the owning
// thread. Cross-block h-exchange per step via flag-array barrier, split by
// bt-group: block (bt,dt) consumes only its own bt-group's 64 batch rows, so
// it polls just that group's 32 flags (lanes 0..31, one flag per lane).
// ---------------------------------------------------------------------------
__global__ __launch_bounds__(256) void lstm_persist(
    bf16* __restrict__ Hb16, const bf16* __restrict__ Whh_b,
    const float* __restrict__ Xpre, const float* __restrict__ mbuf,
    const int* __restrict__ lengths, int* __restrict__ flags)
{
    const int tid = threadIdx.x;
    const int w = tid >> 6, l = tid & 63;
    const int lr = l & 15, lq = l >> 4;
    const int bt = blockIdx.x & 1, dt = blockIdx.x >> 1;
    const int b0 = bt * 64, d0 = dt * 16;

    __shared__ bf16 Bl[64][520];   // 67 KB, +8 pad

    // one-time stage of W_hh slice: row (g*16+dd) <- global row g*512+d0+dd
    for (int u = tid; u < 64 * 64; u += 256) {
        int row = u >> 6, kc = (u & 63) * 8;
        int g = row >> 4, dd = row & 15;
        *(v8bf*)&Bl[row][kc] = *(const v8bf*)&Whh_b[(long)(g * D_ + d0 + dd) * D_ + kc];
    }

    // per-thread state: r=0..3 -> b = b0 + w*16 + lq*4 + r ; d = d0 + lr
    const int d = d0 + lr;
    float m_st[4], h_st[4];
    float xpf[4][4];
    int lenr[4];
    #pragma unroll
    for (int r = 0; r < 4; r++) {
        int b = b0 + w * 16 + lq * 4 + r;
        lenr[r] = lengths[b];
        m_st[r] = mbuf[(long)b * D_ + d];
        h_st[r] = (float)Hb16[(long)b * D_ + d];
        #pragma unroll
        for (int g = 0; g < 4; g++)
            xpf[r][g] = Xpre[(long)b * NG_ + g * D_ + d];
    }
    __syncthreads();

    for (int t = 0; t < T_; t++) {
        // gates = H[t] @ Whh^T : wave w owns m-rows b0+w*16..+15, 4 gate tiles
        const bf16* Arow = Hb16 + (long)t * B_ * D_ + (long)(b0 + w * 16 + lr) * D_;
        v4f acc[4] = {};
        #pragma unroll
        for (int kk = 0; kk < 16; kk++) {
            v8bf a = *(const v8bf*)&Arow[kk * 32 + lq * 8];
            #pragma unroll
            for (int g = 0; g < 4; g++) {
                v8bf bv = *(const v8bf*)&Bl[g * 16 + lr][kk * 32 + lq * 8];
                acc[g] = __builtin_amdgcn_mfma_f32_16x16x32_bf16(a, bv, acc[g], 0, 0, 0);
            }
        }

        bf16* hn = Hb16 + (long)(t + 1) * B_ * D_;
        #pragma unroll
        for (int r = 0; r < 4; r++) {
            int b = b0 + w * 16 + lq * 4 + r;
            float gi = acc[0][r] + xpf[r][0];
            float gf = acc[1][r] + xpf[r][1];
            float gc = acc[2][r] + xpf[r][2];
            float go = acc[3][r] + xpf[r][3];
            gi = 1.f / (1.f + expf(-gi));
            gf = 1.f / (1.f + expf(-gf));
            gc = tanhf(gc);
            go = 1.f / (1.f + expf(-go));
            float m_new = gf * m_st[r] + gi * gc;
            float h_new = go * tanhf(m_new);
            bool active = t < lenr[r];
            m_st[r] = active ? m_new : m_st[r];
            h_st[r] = active ? h_new : h_st[r];
            hn[(long)b * D_ + d] = (bf16)h_st[r];
        }

        if (t + 1 < T_) {
            __syncthreads();               // all waves' h-stores issued
            if (tid == 0) {
                __threadfence();           // release: h-writes device-visible
                __hip_atomic_store(&flags[blockIdx.x * 32], t + 1,
                                   __ATOMIC_RELAXED, __HIP_MEMORY_SCOPE_AGENT);
            }
            // prefetch next step's Xpre while the group's blocks arrive
            #pragma unroll
            for (int r = 0; r < 4; r++) {
                int b = b0 + w * 16 + lq * 4 + r;
                #pragma unroll
                for (int g = 0; g < 4; g++)
                    xpf[r][g] = Xpre[(long)(t + 1) * B_ * NG_ + (long)b * NG_ + g * D_ + d];
            }
            if (w == 0) {                  // lane i (<32) polls group-block i
                int need = t + 1, v = need;
                do {
                    if (l < 32)
                        v = __hip_atomic_load(&flags[(2 * l + bt) * 32],
                                              __ATOMIC_RELAXED, __HIP_MEMORY_SCOPE_AGENT);
                } while (__any(v < need));
                __threadfence();           // acquire
            }
            __syncthreads();
        }
    }
}

// ---------------------------------------------------------------------------
// Attention + context. 4 waves/block share b (Vproj tile staged in LDS once);
// wave owns one t. ctx[b*T+t] = softmax_k(wh.tanh(Vproj+Wg h))@spatial[b]+h_t.
// ---------------------------------------------------------------------------
__global__ __launch_bounds__(256) void attn_kernel(
    const bf16* __restrict__ Hb16, const float* __restrict__ g_all,
    const float* __restrict__ Vproj, const float* __restrict__ wh,
    const bf16* __restrict__ Sp_b, bf16* __restrict__ ctx)
{
    const int w = threadIdx.x >> 6, l = threadIdx.x & 63;
    const int b = blockIdx.x / 5, tg = blockIdx.x % 5;
    const int t = tg * 4 + w;
    const int r = t * 128 + b;
    __shared__ float svp[KK_][53];
    __shared__ float sg[4][64], sal[4][64], swh[64];

    for (int p = threadIdx.x; p < KK_ * 64; p += 256) {
        int k = p >> 6, j = p & 63;
        if (j < KK_) svp[k][j] = Vproj[((long)b * KK_ + k) * NP_ + j];
    }
    if (w == 0) swh[l] = (l < KK_) ? wh[l] : 0.f;
    sg[w][l] = (l < KK_) ? g_all[(long)r * NP_ + l] : 0.f;
    __syncthreads();

    float z = -1e30f;
    if (l < KK_) {
        float a = 0.f;
        for (int j = 0; j < KK_; j++)
            a += swh[j] * tanhf(svp[l][j] + sg[w][j]);
        z = a;
    }
    float mx = z;
    #pragma unroll
    for (int o = 32; o > 0; o >>= 1) mx = fmaxf(mx, __shfl_xor(mx, o));
    float e = (l < KK_) ? expf(z - mx) : 0.f;
    float sm = e;
    #pragma unroll
    for (int o = 32; o > 0; o >>= 1) sm += __shfl_xor(sm, o);
    sal[w][l] = e / sm;
    __syncthreads();

    const bf16* hrow = Hb16 + (long)(t + 1) * B_ * D_ + (long)b * D_;
    const bf16* sp = Sp_b + (long)b * KK_ * D_;
    bf16* crow = ctx + (long)(b * T_ + t) * D_;
    v8bf hro = *(const v8bf*)&hrow[l * 8];
    float c[8] = {};
    for (int k = 0; k < KK_; k++) {
        v8bf s8 = *(const v8bf*)&sp[k * D_ + l * 8];
        float al = sal[w][k];
        #pragma unroll
        for (int e2 = 0; e2 < 8; e2++) c[e2] += al * (float)s8[e2];
    }
    v8bf outv;
    #pragma unroll
    for (int e2 = 0; e2 < 8; e2++) outv[e2] = (bf16)(c[e2] + (float)hro[e2]);
    *(v8bf*)&crow[l * 8] = outv;
}

// ---------------------------------------------------------------------------
extern "C" void kernel_launch(void* const* d_in, const int* in_sizes, int n_in,
                              void* d_out, int out_size, void* d_ws, size_t ws_size,
                              hipStream_t stream)
{
    const float* spatial  = (const float*)d_in[0];
    const float* gfeat    = (const float*)d_in[1];
    const int*   caps     = (const int*)d_in[2];
    const int*   lengths  = (const int*)d_in[3];
    const float* emb      = (const float*)d_in[4];
    const float* W_init_h = (const float*)d_in[5];
    const float* b_init_h = (const float*)d_in[6];
    const float* W_init_m = (const float*)d_in[7];
    const float* b_init_m = (const float*)d_in[8];
    const float* W_ih     = (const float*)d_in[9];
    const float* b_ih     = (const float*)d_in[10];
    const float* W_hh     = (const float*)d_in[11];
    const float* b_hh     = (const float*)d_in[12];
    const float* Wv       = (const float*)d_in[13];
    const float* bv       = (const float*)d_in[14];
    const float* Wg       = (const float*)d_in[15];
    const float* bg       = (const float*)d_in[16];
    const float* wh       = (const float*)d_in[17];
    const float* bh_att   = (const float*)d_in[18];
    const float* Wp       = (const float*)d_in[19];
    const float* bp       = (const float*)d_in[20];
    float* out = (float*)d_out;
    (void)bh_att;

    char* ws = (char*)d_ws;
    size_t off = 0;
    auto alloc = [&](size_t bytes) -> void* {
        off = (off + 255) & ~(size_t)255;
        void* p = ws + off;
        off += bytes;
        return p;
    };

    bf16* Wp_b    = (bf16*)alloc((size_t)VPAD * D_ * 2);
    bf16* Whh_b   = (bf16*)alloc((size_t)NG_ * D_ * 2);
    bf16* Wih_b   = (bf16*)alloc((size_t)NG_ * XK_ * 2);
    bf16* Xin_b   = (bf16*)alloc((size_t)T_ * B_ * XK_ * 2);
    bf16* Sp_b    = (bf16*)alloc((size_t)B_ * KK_ * D_ * 2);
    bf16* Wv_b    = (bf16*)alloc((size_t)NP_ * D_ * 2);
    bf16* Wg_b    = (bf16*)alloc((size_t)NP_ * D_ * 2);
    bf16* Winit2_b= (bf16*)alloc((size_t)2 * D_ * D_ * 2);
    bf16* Gf_b    = (bf16*)alloc((size_t)B_ * D_ * 2);
    float* bias_comb = (float*)alloc(NG_ * 4);
    float* bias_init = (float*)alloc(2 * D_ * 4);
    float* bv_pad    = (float*)alloc(NP_ * 4);
    float* bg_pad    = (float*)alloc(NP_ * 4);
    bf16* Hb16    = (bf16*)alloc((size_t)(T_ + 1) * B_ * D_ * 2);
    float* mbuf   = (float*)alloc((size_t)B_ * D_ * 4);
    float* Xpre   = (float*)alloc((size_t)T_ * B_ * NG_ * 4);
    float* VprojW = (float*)alloc((size_t)B_ * KK_ * NP_ * 4);
    float* g_allW = (float*)alloc((size_t)T_ * B_ * NP_ * 4);
    bf16* ctx     = (bf16*)alloc((size_t)T_ * B_ * D_ * 2);
    int*  flags   = (int*)alloc((size_t)NBLK * 32 * 4);

    // 1. prep / conversions / flag zeroing
    prep_kernel<<<1024, 256, 0, stream>>>(
        spatial, gfeat, caps, emb, W_init_h, b_init_h, W_init_m, b_init_m,
        W_ih, b_ih, W_hh, b_hh, Wv, bv, Wg, bg, Wp,
        Wp_b, Whh_b, Wih_b, Xin_b, Sp_b, Wv_b, Wg_b, Winit2_b, Gf_b,
        bias_comb, bias_init, bv_pad, bg_pad, flags);

    // 2. h0 (bf16 -> Hb16[0]) and m0 (f32 -> mbuf) in one GEMM
    gemm_bt<3><<<dim3(1, 8), 256, 0, stream>>>(Gf_b, Winit2_b, bias_init,
                                               Hb16, mbuf, B_, 2 * D_, D_, 0, 0, nullptr);

    // 3. V_proj = spatial @ Wv^T + bv  -> [B*K, 128] f32
    gemm_bt<0><<<dim3((B_ * KK_) / 128, 1), 256, 0, stream>>>(
        Sp_b, Wv_b, bv_pad, VprojW, nullptr, B_ * KK_, NP_, D_, NP_, 0, nullptr);

    // 4. Xpre = Xin @ W_ih^T + (b_ih + b_hh)  -> [T*B, 2048] f32
    gemm_bt<0><<<dim3((T_ * B_) / 128, NG_ / 128), 256, 0, stream>>>(
        Xin_b, Wih_b, bias_comb, Xpre, nullptr, T_ * B_, NG_, XK_, NG_, 0, nullptr);

    // 5. all 20 LSTM steps: ONE persistent kernel, REGULAR launch, flag barrier
    lstm_persist<<<NBLK, 256, 0, stream>>>(Hb16, Whh_b, Xpre, mbuf, lengths, flags);

    // 6. g_all = H[1..T] @ Wg^T + bg  -> [T*B, 128] f32
    gemm_bt<0><<<dim3((T_ * B_) / 128, 1), 256, 0, stream>>>(
        Hb16 + (size_t)B_ * D_, Wg_b, bg_pad, g_allW, nullptr, T_ * B_, NP_, D_, NP_, 0, nullptr);

    // 7. attention + ctx = c + h  (bf16, rows b*T+t)
    attn_kernel<<<B_ * 5, 256, 0, stream>>>(Hb16, g_allW, VprojW, wh, Sp_b, ctx);

    // 8. logits = ctx @ Wp^T + bp, masked, -> d_out [B*T, V]
    gemm_bt<2><<<dim3((T_ * B_) / 128, VPAD / 128), 256, 0, stream>>>(
        ctx, Wp_b, bp, out, nullptr, T_ * B_, VPAD, D_, V_, V_, lengths);
}